// Round 1
// baseline (1497.055 us; speedup 1.0000x reference)
//
#include <hip/hip_runtime.h>
#include <hip/hip_bf16.h>

// FCCaps capsule routing, MI355X.
// Shapes: x[32,1024,128] f32, w1[1024,20,64,128] f32.
// u_hat[b,n,c,d] = sum_i w1[n,c,d,i]*x[b,n,i]; 3 routing iterations; out = poses[32,20,64,1] ++ act[32,20,1].

#define NCLS 20
#define NIN  1024
#define CIN  128
#define DOUT 64
#define BATCH 32

__device__ __forceinline__ float b2f(unsigned short u) {
    union { unsigned int i; float f; } v; v.i = ((unsigned int)u) << 16; return v.f;
}
__device__ __forceinline__ unsigned short f2b(float f) {
    union { float f; unsigned int i; } v; v.f = f;
    unsigned int x = v.i;
    unsigned int r = (x + 0x7fffu + ((x >> 16) & 1u)) >> 16;   // round-nearest-even
    return (unsigned short)r;
}

// ---------------------------------------------------------------------------
// Pass A: u_hat (bf16) = batched GEMM. grid = 1024 n x 5 cgroups; 256 thr.
// wave -> class (cg*4+wave), lane -> d, per-thread acc over all 32 b.
// W staged to LDS as [c][i][d] with XOR swizzle on d to kill staging-write
// bank conflicts. X read through wave-uniform addresses (scalarizable).
// ---------------------------------------------------------------------------
__global__ __launch_bounds__(256) void pass_uhat(
    const float* __restrict__ x, const float* __restrict__ w1,
    unsigned short* __restrict__ uhat)
{
    const int bx   = blockIdx.x;
    const int n    = bx / 5;
    const int cg   = bx % 5;
    const int t    = threadIdx.x;
    const int wave = t >> 6;
    const int lane = t & 63;
    const int c    = cg * 4 + wave;

    __shared__ float Ws[4][32][64];   // [cc][i][d_swizzled]

    float acc[32];
#pragma unroll
    for (int b = 0; b < 32; ++b) acc[b] = 0.f;

    const float* wbase = w1 + (size_t)(n * NCLS + cg * 4) * (DOUT * CIN);

    for (int it = 0; it < 4; ++it) {          // i-tiles of 32
        __syncthreads();
        // ---- stage: 4c x 64d x 32i, transpose to [c][i][d^swz]
#pragma unroll
        for (int k = 0; k < 8; ++k) {
            int q  = t + k * 256;             // quad id 0..2047
            int qi = q & 7;                   // i4 chunk
            int dd = (q >> 3) & 63;           // d
            int cc = q >> 9;                  // class-in-group
            const float4 v4 = *reinterpret_cast<const float4*>(
                wbase + (size_t)(cc * DOUT + dd) * CIN + it * 32 + qi * 4);
            int dsw = dd ^ (qi << 3);         // qi = (ii>>2)&7 for ii=qi*4+m
            Ws[cc][qi * 4 + 0][dsw] = v4.x;
            Ws[cc][qi * 4 + 1][dsw] = v4.y;
            Ws[cc][qi * 4 + 2][dsw] = v4.z;
            Ws[cc][qi * 4 + 3][dsw] = v4.w;
        }
        __syncthreads();

        float wreg[32];
#pragma unroll
        for (int i = 0; i < 32; ++i)
            wreg[i] = Ws[wave][i][lane ^ (((i >> 2) & 7) << 3)];

        const float* xbase = x + n * CIN + it * 32;
#pragma unroll
        for (int b = 0; b < 32; ++b) {
            const float4* xp = reinterpret_cast<const float4*>(xbase + ((size_t)b << 17));
            float a = acc[b];
#pragma unroll
            for (int s = 0; s < 8; ++s) {
                float4 xq = xp[s];            // wave-uniform address
                a = fmaf(wreg[s * 4 + 0], xq.x, a);
                a = fmaf(wreg[s * 4 + 1], xq.y, a);
                a = fmaf(wreg[s * 4 + 2], xq.z, a);
                a = fmaf(wreg[s * 4 + 3], xq.w, a);
            }
            acc[b] = a;
        }
    }

    unsigned short* obase = uhat + (size_t)(n * NCLS + c) * DOUT + lane;
#pragma unroll
    for (int b = 0; b < 32; ++b)
        obase[(size_t)b * (NIN * NCLS * DOUT)] = f2b(acc[b]);
}

// ---------------------------------------------------------------------------
// Pass S0: s0_raw[b,c,d] = sum_n u_hat[b,n,c,d].  grid = 32b x 20c x 8 chunks.
// ---------------------------------------------------------------------------
__global__ __launch_bounds__(256) void pass_s0(
    const unsigned short* __restrict__ uhat, float* __restrict__ s0raw)
{
    const int bx    = blockIdx.x;
    const int chunk = bx & 7;
    const int c     = (bx >> 3) % 20;
    const int b     = bx / 160;
    const int t     = threadIdx.x;
    const int wave  = t >> 6;
    const int lane  = t & 63;

    const unsigned short* base = uhat + (size_t)b * (NIN * NCLS * DOUT)
                               + (size_t)(chunk * 128 + wave * 32) * (NCLS * DOUT)
                               + c * DOUT + lane;
    float acc = 0.f;
#pragma unroll 8
    for (int k = 0; k < 32; ++k) acc += b2f(base[(size_t)k * (NCLS * DOUT)]);

    __shared__ float red[4][64];
    red[wave][lane] = acc;
    __syncthreads();
    if (wave == 0) {
        float v = red[0][lane] + red[1][lane] + red[2][lane] + red[3][lane];
        atomicAdd(&s0raw[(size_t)(b * NCLS + c) * DOUT + lane], v);
    }
}

// ---------------------------------------------------------------------------
// Pass V: v = squash(s_raw * inv), inv = 1/Z[b,c] or uniform 1/1024.
// grid = 640 (b*20+c), 64 threads (lane = d). Optional final output write.
// ---------------------------------------------------------------------------
__global__ void pass_v(const float* __restrict__ sraw, const float* __restrict__ Zc,
                       float invz_uniform, float* __restrict__ vbuf,
                       float* __restrict__ vn2,
                       float* __restrict__ out_poses, float* __restrict__ out_act)
{
    const int bc   = blockIdx.x;
    const int lane = threadIdx.x;
    const int idx  = bc * 64 + lane;
    float inv = (Zc != nullptr) ? (1.0f / Zc[bc]) : invz_uniform;
    float s  = sraw[idx] * inv;
    float s2 = s * s;
#pragma unroll
    for (int o = 32; o >= 1; o >>= 1) s2 += __shfl_xor(s2, o, 64);
    float norm  = sqrtf(s2);
    float scale = norm / (0.5f + s2);
    float v = scale * s;
    vbuf[idx] = v;
    float vn = scale * scale * s2;             // |v|^2
    if (lane == 0) vn2[bc] = vn;
    if (out_poses != nullptr) {
        out_poses[idx] = v;
        if (lane == 0) out_act[bc] = sqrtf(vn);
    }
}

// ---------------------------------------------------------------------------
// Pass ROUTE (one routing iteration, fused):
//   per (b,n): q_c=|u|^2, p_c=u.v ; dd = 1 - su^2 q + 2 su p - |v|^2 ;
//   b_ij += dd ; softc = softmax_c(b_ij) ; accumulate s'= sum softc*u, Z=sum softc.
// grid = 32b x 32 n-chunks (32 n/block, 8 n/wave); 256 threads.
// ---------------------------------------------------------------------------
__global__ __launch_bounds__(256) void pass_route(
    const unsigned short* __restrict__ uhat, const float* __restrict__ vbuf,
    const float* __restrict__ vn2, float* __restrict__ bij,
    float* __restrict__ snext, float* __restrict__ Znext)
{
    const int b     = blockIdx.x >> 5;
    const int chunk = blockIdx.x & 31;
    const int t     = threadIdx.x;
    const int wave  = t >> 6;
    const int lane  = t & 63;

    __shared__ float Vs[20 * 65];          // v[c][d], stride 65 (bank-friendly)
    __shared__ float sred[4][20 * 65];     // per-wave s' partials
    __shared__ float qrow[4][20], prow[4][20], scrow[4][20], zred[4][20];

    for (int idx = t; idx < 20 * 65; idx += 256) {
        int cc = idx / 65, dd = idx % 65;
        Vs[idx] = (dd < 64) ? vbuf[(size_t)b * (NCLS * DOUT) + cc * 64 + dd] : 0.f;
    }
    __syncthreads();

    const int cmy   = lane >> 4;           // which of the 4 classes in a load
    const int dbase = (lane & 15) * 4;
    const float vnb = vn2[b * NCLS + (lane < 20 ? lane : 0)];

    float sacc[5][4];
#pragma unroll
    for (int tt = 0; tt < 5; ++tt)
#pragma unroll
        for (int j = 0; j < 4; ++j) sacc[tt][j] = 0.f;
    float zacc = 0.f;

    for (int k = 0; k < 8; ++k) {
        const int n = chunk * 32 + wave * 8 + k;
        const ushort4* up = reinterpret_cast<const ushort4*>(
            uhat + ((size_t)b * NIN + n) * (NCLS * DOUT));

        float uf[5][4];
#pragma unroll
        for (int tt = 0; tt < 5; ++tt) {
            ushort4 uq = up[tt * 64 + lane];
            uf[tt][0] = b2f(uq.x); uf[tt][1] = b2f(uq.y);
            uf[tt][2] = b2f(uq.z); uf[tt][3] = b2f(uq.w);
        }
        // q,p partials + 16-lane-group reduction (one class per group)
#pragma unroll
        for (int tt = 0; tt < 5; ++tt) {
            int cc = tt * 4 + cmy;
            float q = 0.f, p = 0.f;
#pragma unroll
            for (int j = 0; j < 4; ++j) {
                float u = uf[tt][j];
                q = fmaf(u, u, q);
                p = fmaf(u, Vs[cc * 65 + dbase + j], p);
            }
#pragma unroll
            for (int o = 8; o >= 1; o >>= 1) {
                q += __shfl_xor(q, o, 16);
                p += __shfl_xor(p, o, 16);
            }
            if ((lane & 15) == 0) { qrow[wave][cc] = q; prow[wave][cc] = p; }
        }
        __syncthreads();
        // routing logit update + softmax over classes (lanes 0..19 of wave)
        {
            float val = -1e30f;
            if (lane < 20) {
                float q  = qrow[wave][lane];
                float p  = prow[wave][lane];
                float qs = sqrtf(q);
                float su = qs / (0.5f + q);
                float dd = 1.f - su * su * q + 2.f * su * p - vnb;
                size_t bidx = ((size_t)b * NIN + n) * NCLS + lane;
                float bnew = bij[bidx] + dd;
                bij[bidx] = bnew;
                val = bnew;
            }
            float mx = val;
#pragma unroll
            for (int o = 16; o >= 1; o >>= 1) mx = fmaxf(mx, __shfl_xor(mx, o, 32));
            float e = (lane < 20) ? __expf(val - mx) : 0.f;
            float se = e;
#pragma unroll
            for (int o = 16; o >= 1; o >>= 1) se += __shfl_xor(se, o, 32);
            if (lane < 20) {
                float sc = e / se;
                scrow[wave][lane] = sc;
                zacc += sc;
            }
        }
        __syncthreads();
        // accumulate s' in registers (lane's (c,d) slots are n-invariant)
#pragma unroll
        for (int tt = 0; tt < 5; ++tt) {
            float sc = scrow[wave][tt * 4 + cmy];
#pragma unroll
            for (int j = 0; j < 4; ++j)
                sacc[tt][j] = fmaf(sc, uf[tt][j], sacc[tt][j]);
        }
    }

    // per-wave partials -> LDS -> block reduce -> global atomics
#pragma unroll
    for (int tt = 0; tt < 5; ++tt) {
        int cc = tt * 4 + cmy;
#pragma unroll
        for (int j = 0; j < 4; ++j)
            sred[wave][cc * 65 + dbase + j] = sacc[tt][j];
    }
    if (lane < 20) zred[wave][lane] = zacc;
    __syncthreads();

    for (int idx = t; idx < NCLS * DOUT; idx += 256) {
        int cc = idx >> 6, dd = idx & 63;
        int a  = cc * 65 + dd;
        float sum = sred[0][a] + sred[1][a] + sred[2][a] + sred[3][a];
        atomicAdd(&snext[(size_t)(b * NCLS + cc) * DOUT + dd], sum);
    }
    if (t < 20) {
        float z = zred[0][t] + zred[1][t] + zred[2][t] + zred[3][t];
        atomicAdd(&Znext[b * NCLS + t], z);
    }
}

// ---------------------------------------------------------------------------
extern "C" void kernel_launch(void* const* d_in, const int* in_sizes, int n_in,
                              void* d_out, int out_size, void* d_ws, size_t ws_size,
                              hipStream_t stream)
{
    (void)in_sizes; (void)n_in; (void)out_size; (void)ws_size;
    const float* x  = (const float*)d_in[0];
    const float* w1 = (const float*)d_in[1];
    float* out = (float*)d_out;

    char* ws = (char*)d_ws;
    unsigned short* uhat = (unsigned short*)ws;                 // 32*1024*20*64 * 2B
    size_t off = (size_t)BATCH * NIN * NCLS * DOUT * 2;         // 83,886,080
    float* s0   = (float*)(ws + off); off += (size_t)BATCH * NCLS * DOUT * 4;   // 163840
    float* s1   = (float*)(ws + off); off += (size_t)BATCH * NCLS * DOUT * 4;
    float* s2   = (float*)(ws + off); off += (size_t)BATCH * NCLS * DOUT * 4;
    float* Z1   = (float*)(ws + off); off += (size_t)BATCH * NCLS * 4;          // 2560
    float* Z2   = (float*)(ws + off); off += (size_t)BATCH * NCLS * 4;
    float* bij  = (float*)(ws + off); off += (size_t)BATCH * NIN * NCLS * 4;    // 2,621,440
    float* vbuf = (float*)(ws + off); off += (size_t)BATCH * NCLS * DOUT * 4;
    float* vn2  = (float*)(ws + off); off += (size_t)BATCH * NCLS * 4;

    // zero accumulators + b_ij (contiguous region: s0..bij)
    size_t zbytes = (size_t)3 * BATCH * NCLS * DOUT * 4 + 2 * BATCH * NCLS * 4
                  + (size_t)BATCH * NIN * NCLS * 4;
    hipMemsetAsync(s0, 0, zbytes, stream);

    pass_uhat <<<NIN * 5, 256, 0, stream>>>(x, w1, uhat);
    pass_s0   <<<BATCH * NCLS * 8, 256, 0, stream>>>(uhat, s0);
    pass_v    <<<BATCH * NCLS, 64, 0, stream>>>(s0, nullptr, 1.0f / 1024.0f,
                                                vbuf, vn2, nullptr, nullptr);
    pass_route<<<BATCH * 32, 256, 0, stream>>>(uhat, vbuf, vn2, bij, s1, Z1);
    pass_v    <<<BATCH * NCLS, 64, 0, stream>>>(s1, Z1, 0.f, vbuf, vn2, nullptr, nullptr);
    pass_route<<<BATCH * 32, 256, 0, stream>>>(uhat, vbuf, vn2, bij, s2, Z2);
    pass_v    <<<BATCH * NCLS, 64, 0, stream>>>(s2, Z2, 0.f, vbuf, vn2,
                                                out, out + BATCH * NCLS * DOUT);
}

// Round 2
// 1010.062 us; speedup vs baseline: 1.4821x; 1.4821x over previous
//
#include <hip/hip_runtime.h>
#include <hip/hip_bf16.h>

// FCCaps capsule routing, MI355X.
// x[32,1024,128] f32, w1[1024,20,64,128] f32.
// u_hat[b,n,c,d] = sum_i w1[n,c,d,i]*x[b,n,i]; 3 routing iterations;
// out = poses[32,20,64,1] ++ activations[32,20,1].

#define NCLS 20
#define NIN  1024
#define CIN  128
#define DOUT 64
#define BATCH 32
#define MCD  1280   // NCLS*DOUT flattened

typedef __attribute__((ext_vector_type(8))) short bf16x8;
typedef __attribute__((ext_vector_type(4))) float f32x4;

__device__ __forceinline__ float b2f(unsigned short u) {
    union { unsigned int i; float f; } v; v.i = ((unsigned int)u) << 16; return v.f;
}
__device__ __forceinline__ unsigned short f2b_rne(float f) {
    union { float f; unsigned int i; } v; v.f = f;
    unsigned int x = v.i;
    return (unsigned short)((x + 0x7fffu + ((x >> 16) & 1u)) >> 16);
}
// split 8 fp32 into hi-bf16 + lo-bf16 (residual) fragments
__device__ __forceinline__ void cvt_hilo(const float* v, bf16x8& h, bf16x8& l) {
#pragma unroll
    for (int j = 0; j < 8; ++j) {
        unsigned short hb = f2b_rne(v[j]);
        h[j] = (short)hb;
        l[j] = (short)f2b_rne(v[j] - b2f(hb));
    }
}

// ---------------------------------------------------------------------------
// Pass A (MFMA): per n, D[b=32, cd=1280] = x[32,128] * w1[n]^T[128,1280].
// grid = 1024 n x 2 halves; 256 thr = 4 waves; wave handles 10 nt (16-col tiles).
// A = x: 8 frags (2 mt x 4 ks) hi/lo, loaded once. B = w1: streamed, 2 float4
// per lane per (nt,ks) = 16 rows x 128 B coalesced. 3-term hi/lo MFMA keeps
// fp32-grade u_hat; only bf16 store rounding remains (same error as R1).
// D layout (HW-verified): row(b) = (lane>>4)*4+reg, col(cd) = lane&15.
// ---------------------------------------------------------------------------
__global__ __launch_bounds__(256) void pass_uhat(
    const float* __restrict__ x, const float* __restrict__ W,
    unsigned short* __restrict__ uhat)
{
    const int n    = blockIdx.x >> 1;
    const int half = blockIdx.x & 1;
    const int t    = threadIdx.x;
    const int wave = t >> 6;
    const int lane = t & 63;
    const int lm   = lane & 15;
    const int lq   = lane >> 4;

    // ---- A-fragments (x) in registers, hi/lo split
    bf16x8 xh[2][4], xl[2][4];
#pragma unroll
    for (int mt = 0; mt < 2; ++mt) {
        const float* xrow = x + ((size_t)(mt * 16 + lm) * NIN + n) * CIN + lq * 8;
#pragma unroll
        for (int ks = 0; ks < 4; ++ks) {
            float v[8];
            *reinterpret_cast<float4*>(&v[0]) = *reinterpret_cast<const float4*>(xrow + ks * 32);
            *reinterpret_cast<float4*>(&v[4]) = *reinterpret_cast<const float4*>(xrow + ks * 32 + 4);
            cvt_hilo(v, xh[mt][ks], xl[mt][ks]);
        }
    }

    const int nt0 = half * 40 + wave * 10;
    for (int ntc = 0; ntc < 10; ++ntc) {
        const int nt = nt0 + ntc;
        const float* wp = W + ((size_t)n * MCD + nt * 16 + lm) * CIN + lq * 8;
        f32x4 acc0 = {0.f, 0.f, 0.f, 0.f};
        f32x4 acc1 = {0.f, 0.f, 0.f, 0.f};
#pragma unroll
        for (int ks = 0; ks < 4; ++ks) {
            float v[8];
            *reinterpret_cast<float4*>(&v[0]) = *reinterpret_cast<const float4*>(wp + ks * 32);
            *reinterpret_cast<float4*>(&v[4]) = *reinterpret_cast<const float4*>(wp + ks * 32 + 4);
            bf16x8 wh, wl;
            cvt_hilo(v, wh, wl);
            acc0 = __builtin_amdgcn_mfma_f32_16x16x32_bf16(xh[0][ks], wh, acc0, 0, 0, 0);
            acc1 = __builtin_amdgcn_mfma_f32_16x16x32_bf16(xh[1][ks], wh, acc1, 0, 0, 0);
            acc0 = __builtin_amdgcn_mfma_f32_16x16x32_bf16(xh[0][ks], wl, acc0, 0, 0, 0);
            acc1 = __builtin_amdgcn_mfma_f32_16x16x32_bf16(xh[1][ks], wl, acc1, 0, 0, 0);
            acc0 = __builtin_amdgcn_mfma_f32_16x16x32_bf16(xl[0][ks], wh, acc0, 0, 0, 0);
            acc1 = __builtin_amdgcn_mfma_f32_16x16x32_bf16(xl[1][ks], wh, acc1, 0, 0, 0);
        }
        const int cd = nt * 16 + lm;
#pragma unroll
        for (int mt = 0; mt < 2; ++mt) {
            f32x4 a = mt ? acc1 : acc0;
#pragma unroll
            for (int r = 0; r < 4; ++r) {
                int br = mt * 16 + lq * 4 + r;
                uhat[((size_t)br * NIN + n) * MCD + cd] = f2b_rne(a[r]);
            }
        }
    }
}

// ---------------------------------------------------------------------------
// Pass S0: s0_raw[b,cd] = sum_n u_hat[b,n,cd]. grid = 32 b x 16 n-chunks,
// block = 320 threads: thread t owns ushort4 #t of each 2560-B row (perfectly
// coalesced streaming), accumulates over 64 n, 4 atomics at the end.
// ---------------------------------------------------------------------------
__global__ __launch_bounds__(320) void pass_s0(
    const unsigned short* __restrict__ uhat, float* __restrict__ s0raw)
{
    const int b     = blockIdx.x >> 4;
    const int chunk = blockIdx.x & 15;
    const int t     = threadIdx.x;          // 0..319

    const ushort4* base = reinterpret_cast<const ushort4*>(
        uhat + ((size_t)b * NIN + chunk * 64) * MCD) + t;
    float a0 = 0.f, a1 = 0.f, a2 = 0.f, a3 = 0.f;
#pragma unroll 4
    for (int k = 0; k < 64; ++k) {
        ushort4 u = base[(size_t)k * 320];
        a0 += b2f(u.x); a1 += b2f(u.y); a2 += b2f(u.z); a3 += b2f(u.w);
    }
    float* dst = s0raw + (size_t)b * MCD + t * 4;
    atomicAdd(dst + 0, a0);
    atomicAdd(dst + 1, a1);
    atomicAdd(dst + 2, a2);
    atomicAdd(dst + 3, a3);
}

// ---------------------------------------------------------------------------
// Pass V: v = squash(s_raw * inv). grid = 640 (b*20+c), 64 thr (lane = d).
// ---------------------------------------------------------------------------
__global__ void pass_v(const float* __restrict__ sraw, const float* __restrict__ Zc,
                       float invz_uniform, float* __restrict__ vbuf,
                       float* __restrict__ vn2,
                       float* __restrict__ out_poses, float* __restrict__ out_act)
{
    const int bc   = blockIdx.x;
    const int lane = threadIdx.x;
    const int idx  = bc * 64 + lane;
    float inv = (Zc != nullptr) ? (1.0f / Zc[bc]) : invz_uniform;
    float s  = sraw[idx] * inv;
    float s2 = s * s;
#pragma unroll
    for (int o = 32; o >= 1; o >>= 1) s2 += __shfl_xor(s2, o, 64);
    float norm  = sqrtf(s2);
    float scale = norm / (0.5f + s2);
    float v = scale * s;
    vbuf[idx] = v;
    float vn = scale * scale * s2;             // |v|^2
    if (lane == 0) vn2[bc] = vn;
    if (out_poses != nullptr) {
        out_poses[idx] = v;
        if (lane == 0) out_act[bc] = sqrtf(vn);
    }
}

// ---------------------------------------------------------------------------
// Pass ROUTE (one routing iteration, fused). grid = 32b x 32 n-chunks;
// 256 thr; 8 n per wave. All per-k LDS traffic is wave-local -> no barriers
// inside the k-loop (only the initial Vs fill and the final block reduce).
// ---------------------------------------------------------------------------
__global__ __launch_bounds__(256) void pass_route(
    const unsigned short* __restrict__ uhat, const float* __restrict__ vbuf,
    const float* __restrict__ vn2, float* __restrict__ bij,
    float* __restrict__ snext, float* __restrict__ Znext)
{
    const int b     = blockIdx.x >> 5;
    const int chunk = blockIdx.x & 31;
    const int t     = threadIdx.x;
    const int wave  = t >> 6;
    const int lane  = t & 63;

    __shared__ float Vs[20 * 65];          // v[c][d], stride 65
    __shared__ float sred[4][20 * 65];     // per-wave s' partials
    __shared__ float qrow[4][20], prow[4][20], scrow[4][20], zred[4][20];

    for (int idx = t; idx < 20 * 65; idx += 256) {
        int cc = idx / 65, dd = idx % 65;
        Vs[idx] = (dd < 64) ? vbuf[(size_t)b * MCD + cc * 64 + dd] : 0.f;
    }
    __syncthreads();

    const int cmy   = lane >> 4;
    const int dbase = (lane & 15) * 4;
    const float vnb = vn2[b * NCLS + (lane < 20 ? lane : 0)];

    float sacc[5][4];
#pragma unroll
    for (int tt = 0; tt < 5; ++tt)
#pragma unroll
        for (int j = 0; j < 4; ++j) sacc[tt][j] = 0.f;
    float zacc = 0.f;

    for (int k = 0; k < 8; ++k) {
        const int n = chunk * 32 + wave * 8 + k;
        const ushort4* up = reinterpret_cast<const ushort4*>(
            uhat + ((size_t)b * NIN + n) * MCD);

        float uf[5][4];
#pragma unroll
        for (int tt = 0; tt < 5; ++tt) {
            ushort4 uq = up[tt * 64 + lane];
            uf[tt][0] = b2f(uq.x); uf[tt][1] = b2f(uq.y);
            uf[tt][2] = b2f(uq.z); uf[tt][3] = b2f(uq.w);
        }
#pragma unroll
        for (int tt = 0; tt < 5; ++tt) {
            int cc = tt * 4 + cmy;
            float q = 0.f, p = 0.f;
#pragma unroll
            for (int j = 0; j < 4; ++j) {
                float u = uf[tt][j];
                q = fmaf(u, u, q);
                p = fmaf(u, Vs[cc * 65 + dbase + j], p);
            }
#pragma unroll
            for (int o = 8; o >= 1; o >>= 1) {
                q += __shfl_xor(q, o, 16);
                p += __shfl_xor(p, o, 16);
            }
            if ((lane & 15) == 0) { qrow[wave][cc] = q; prow[wave][cc] = p; }
        }
        // wave-local: LDS write->read ordered by lgkmcnt, no block barrier
        {
            float val = -1e30f;
            if (lane < 20) {
                float q  = qrow[wave][lane];
                float p  = prow[wave][lane];
                float qs = sqrtf(q);
                float su = qs / (0.5f + q);
                float dd = 1.f - su * su * q + 2.f * su * p - vnb;
                size_t bidx = ((size_t)b * NIN + n) * NCLS + lane;
                float bnew = bij[bidx] + dd;
                bij[bidx] = bnew;
                val = bnew;
            }
            float mx = val;
#pragma unroll
            for (int o = 16; o >= 1; o >>= 1) mx = fmaxf(mx, __shfl_xor(mx, o, 32));
            float e = (lane < 20) ? __expf(val - mx) : 0.f;
            float se = e;
#pragma unroll
            for (int o = 16; o >= 1; o >>= 1) se += __shfl_xor(se, o, 32);
            if (lane < 20) {
                float sc = e / se;
                scrow[wave][lane] = sc;
                zacc += sc;
            }
        }
#pragma unroll
        for (int tt = 0; tt < 5; ++tt) {
            float sc = scrow[wave][tt * 4 + cmy];
#pragma unroll
            for (int j = 0; j < 4; ++j)
                sacc[tt][j] = fmaf(sc, uf[tt][j], sacc[tt][j]);
        }
    }

#pragma unroll
    for (int tt = 0; tt < 5; ++tt) {
        int cc = tt * 4 + cmy;
#pragma unroll
        for (int j = 0; j < 4; ++j)
            sred[wave][cc * 65 + dbase + j] = sacc[tt][j];
    }
    if (lane < 20) zred[wave][lane] = zacc;
    __syncthreads();

    for (int idx = t; idx < NCLS * DOUT; idx += 256) {
        int cc = idx >> 6, dd = idx & 63;
        int a  = cc * 65 + dd;
        float sum = sred[0][a] + sred[1][a] + sred[2][a] + sred[3][a];
        atomicAdd(&snext[(size_t)(b * NCLS + cc) * DOUT + dd], sum);
    }
    if (t < 20) {
        float z = zred[0][t] + zred[1][t] + zred[2][t] + zred[3][t];
        atomicAdd(&Znext[b * NCLS + t], z);
    }
}

// ---------------------------------------------------------------------------
extern "C" void kernel_launch(void* const* d_in, const int* in_sizes, int n_in,
                              void* d_out, int out_size, void* d_ws, size_t ws_size,
                              hipStream_t stream)
{
    (void)in_sizes; (void)n_in; (void)out_size; (void)ws_size;
    const float* x  = (const float*)d_in[0];
    const float* w1 = (const float*)d_in[1];
    float* out = (float*)d_out;

    char* ws = (char*)d_ws;
    unsigned short* uhat = (unsigned short*)ws;                 // 32*1024*1280 * 2B
    size_t off = (size_t)BATCH * NIN * MCD * 2;                 // 83,886,080
    float* s0   = (float*)(ws + off); off += (size_t)BATCH * MCD * 4;
    float* s1   = (float*)(ws + off); off += (size_t)BATCH * MCD * 4;
    float* s2   = (float*)(ws + off); off += (size_t)BATCH * MCD * 4;
    float* Z1   = (float*)(ws + off); off += (size_t)BATCH * NCLS * 4;
    float* Z2   = (float*)(ws + off); off += (size_t)BATCH * NCLS * 4;
    float* bij  = (float*)(ws + off); off += (size_t)BATCH * NIN * NCLS * 4;
    float* vbuf = (float*)(ws + off); off += (size_t)BATCH * MCD * 4;
    float* vn2  = (float*)(ws + off); off += (size_t)BATCH * NCLS * 4;

    // zero accumulators + b_ij (contiguous region: s0..bij)
    size_t zbytes = (size_t)3 * BATCH * MCD * 4 + 2 * BATCH * NCLS * 4
                  + (size_t)BATCH * NIN * NCLS * 4;
    hipMemsetAsync(s0, 0, zbytes, stream);

    pass_uhat <<<NIN * 2, 256, 0, stream>>>(x, w1, uhat);
    pass_s0   <<<BATCH * 16, 320, 0, stream>>>(uhat, s0);
    pass_v    <<<BATCH * NCLS, 64, 0, stream>>>(s0, nullptr, 1.0f / 1024.0f,
                                                vbuf, vn2, nullptr, nullptr);
    pass_route<<<BATCH * 32, 256, 0, stream>>>(uhat, vbuf, vn2, bij, s1, Z1);
    pass_v    <<<BATCH * NCLS, 64, 0, stream>>>(s1, Z1, 0.f, vbuf, vn2, nullptr, nullptr);
    pass_route<<<BATCH * 32, 256, 0, stream>>>(uhat, vbuf, vn2, bij, s2, Z2);
    pass_v    <<<BATCH * NCLS, 64, 0, stream>>>(s2, Z2, 0.f, vbuf, vn2,
                                                out, out + BATCH * MCD);
}